// Round 1
// baseline (808.443 us; speedup 1.0000x reference)
//
#include <hip/hip_runtime.h>

#define HW   65536
#define CIN  192
#define TILE 32

// Fused DegradationInteractionGraph kernel, fp32 VALU version.
// One workgroup = 32 consecutive pixels of one (b, h) row; 256 threads.
// Phases: load x-tile -> a/c GEMM -> gates (gelu/sigmoid) -> acc tile -> Wf matvec.
__global__ __launch_bounds__(256, 2) void dig_fused(
    const float* __restrict__ x,    // [4][192][65536]
    const float* __restrict__ W1,   // [128][64]
    const float* __restrict__ b1,   // [64]
    const float* __restrict__ W2,   // [64]
    const float* __restrict__ b2,   // [1]
    const float* __restrict__ Wf,   // [192][64]
    const float* __restrict__ bf,   // [64]
    float* __restrict__ out)        // [4][64][65536]
{
    __shared__ __align__(16) float xs[CIN * TILE];   // 24 KiB: x tile [c][p]
    __shared__ __align__(16) float ac[384 * TILE];   // 48 KiB: a/c tile, later acc tile
    __shared__ float gates[6 * TILE];

    const int tid  = threadIdx.x;
    const int tile = blockIdx.x;
    const int b    = tile >> 11;             // tile*32 / 65536
    const int hw0  = (tile & 2047) * TILE;

    const float* xbase = x + (size_t)b * (CIN * HW) + hw0;

    // ---- Phase 1: stage x tile (coalesced: 32-contiguous segments) ----
    for (int idx = tid; idx < CIN * TILE; idx += 256) {
        int c = idx >> 5;
        int p = idx & 31;
        xs[idx] = xbase[(size_t)c * HW + p];
    }
    __syncthreads();

    // ---- Phase B: ac[t*128 + kind*64 + e][p] = sum_d xs[t*64+d][p] * W1[(kind*64+d)*64+e]
    // 4x4 register tile per thread: 4 e-values x 4 pixels.
    {
        const int p0   = (tid & 7) * 4;       // 8 pixel groups
        const int r0   = (tid >> 3) * 4;      // 32 row groups, 0..124
        const int kind = r0 >> 6;             // 0 = a (W1 rows 0..63), 1 = c (rows 64..127)
        const int e0   = r0 & 63;

        for (int t = 0; t < 3; ++t) {
            float acc[4][4];
            #pragma unroll
            for (int k = 0; k < 4; ++k)
                #pragma unroll
                for (int l = 0; l < 4; ++l) acc[k][l] = 0.f;

            const float* xrow = xs + (t * 64) * TILE + p0;
            const float* wrow = W1 + (kind * 64) * 64 + e0;

            #pragma unroll 4
            for (int d = 0; d < 64; ++d) {
                float4 xv = *(const float4*)xrow;
                float4 wv = *(const float4*)wrow;
                xrow += TILE;
                wrow += 64;
                float xa[4] = {xv.x, xv.y, xv.z, xv.w};
                float wa[4] = {wv.x, wv.y, wv.z, wv.w};
                #pragma unroll
                for (int k = 0; k < 4; ++k)
                    #pragma unroll
                    for (int l = 0; l < 4; ++l)
                        acc[k][l] += wa[k] * xa[l];
            }

            float* dst = ac + (t * 128 + r0) * TILE + p0;
            #pragma unroll
            for (int k = 0; k < 4; ++k)
                *(float4*)(dst + k * TILE) =
                    make_float4(acc[k][0], acc[k][1], acc[k][2], acc[k][3]);
        }
    }
    __syncthreads();

    // ---- Phase C: gates s_ij = sigmoid(W2 . gelu(a_i + c_j + b1) + b2) ----
    if (tid < 192) {
        const int pair = tid >> 5;            // (0,1),(0,2),(1,0),(1,2),(2,0),(2,1)
        const int p    = tid & 31;
        const int i    = pair >> 1;
        const int j0c  = (i == 0) ? 1 : 0;
        const int j1c  = (i == 2) ? 1 : 2;
        const int j    = (pair & 1) ? j1c : j0c;

        const float* arow = ac + (i * 128) * TILE + p;        // a_i[e]
        const float* crow = ac + (j * 128 + 64) * TILE + p;   // c_j[e]
        float g = 0.f;
        for (int e = 0; e < 64; ++e) {
            float hv  = arow[e * TILE] + crow[e * TILE] + b1[e];
            float cdf = 0.5f * (1.0f + erff(hv * 0.7071067811865476f));
            g += W2[e] * (hv * cdf);          // exact gelu
        }
        g += b2[0];
        gates[pair * TILE + p] = 1.0f / (1.0f + __expf(-g));
    }
    __syncthreads();

    // ---- Phase D: acc_i[d][p] = x_i[d][p] + s_ij0 * x_j0[d][p] + s_ij1 * x_j1[d][p]
    // (stored over the now-dead ac tile, rows 0..191)
    for (int idx = tid; idx < CIN * TILE; idx += 256) {
        int r = idx >> 5;                     // i*64 + d
        int p = idx & 31;
        int i = r >> 6;
        int d = r & 63;
        int j0c = (i == 0) ? 1 : 0;
        int j1c = (i == 2) ? 1 : 2;
        int pi0 = i * 2 + ((j0c > i) ? (j0c - 1) : j0c);
        int pi1 = i * 2 + ((j1c > i) ? (j1c - 1) : j1c);
        float v = xs[idx]
                + gates[pi0 * TILE + p] * xs[(j0c * 64 + d) * TILE + p]
                + gates[pi1 * TILE + p] * xs[(j1c * 64 + d) * TILE + p];
        ac[idx] = v;
    }
    __syncthreads();

    // ---- Phase E: out[o][p] = bf[o] + sum_c acc[c][p] * Wf[c*64+o] ----
    // 2 o-values x 4 pixels per thread.
    {
        const int p0 = (tid & 7) * 4;
        const int o0 = (tid >> 3) * 2;        // 0..62 (even)
        float a0[4] = {0.f, 0.f, 0.f, 0.f};
        float a1[4] = {0.f, 0.f, 0.f, 0.f};

        #pragma unroll 4
        for (int c = 0; c < CIN; ++c) {
            float4 av = *(const float4*)(ac + c * TILE + p0);
            float2 wv = *(const float2*)(Wf + c * 64 + o0);
            float aa[4] = {av.x, av.y, av.z, av.w};
            #pragma unroll
            for (int l = 0; l < 4; ++l) {
                a0[l] += wv.x * aa[l];
                a1[l] += wv.y * aa[l];
            }
        }
        const float bf0 = bf[o0];
        const float bf1 = bf[o0 + 1];
        float* obase = out + (size_t)b * (64 * HW) + hw0 + p0;
        *(float4*)(obase + (size_t)o0 * HW) =
            make_float4(a0[0] + bf0, a0[1] + bf0, a0[2] + bf0, a0[3] + bf0);
        *(float4*)(obase + (size_t)(o0 + 1) * HW) =
            make_float4(a1[0] + bf1, a1[1] + bf1, a1[2] + bf1, a1[3] + bf1);
    }
}

extern "C" void kernel_launch(void* const* d_in, const int* in_sizes, int n_in,
                              void* d_out, int out_size, void* d_ws, size_t ws_size,
                              hipStream_t stream) {
    (void)in_sizes; (void)n_in; (void)out_size; (void)d_ws; (void)ws_size;
    const float* x  = (const float*)d_in[0];
    const float* W1 = (const float*)d_in[1];
    const float* b1 = (const float*)d_in[2];
    const float* W2 = (const float*)d_in[3];
    const float* b2 = (const float*)d_in[4];
    const float* Wf = (const float*)d_in[5];
    const float* bf = (const float*)d_in[6];
    float* out = (float*)d_out;

    dig_fused<<<dim3(8192), dim3(256), 0, stream>>>(x, W1, b1, W2, b2, Wf, bf, out);
}

// Round 2
// 444.973 us; speedup vs baseline: 1.8168x; 1.8168x over previous
//
#include <hip/hip_runtime.h>

#define HW 65536

typedef __attribute__((ext_vector_type(8))) short short8;   // 8 bf16 = 4 VGPRs (MFMA A/B frag)
typedef __attribute__((ext_vector_type(4))) float f32x4;    // MFMA C/D frag

__device__ __forceinline__ unsigned short f2bf(float f) {
    unsigned int u = __float_as_uint(f);
    u += 0x7FFFu + ((u >> 16) & 1u);        // round-to-nearest-even (inputs finite)
    return (unsigned short)(u >> 16);
}
__device__ __forceinline__ float bf2f(unsigned short s) {
    return __uint_as_float(((unsigned int)s) << 16);
}

// ---- prep: transpose weights to bf16 in workspace ----
// w1t[r][d], r = kind*64 + e (128 rows x 64): = W1[kind*64 + d][e]
// wft[o][c] (64 rows x 192):                  = Wf[c][o]
__global__ void dig_prep(const float* __restrict__ W1, const float* __restrict__ Wf,
                         unsigned short* __restrict__ w1t, unsigned short* __restrict__ wft) {
    int tid = blockIdx.x * blockDim.x + threadIdx.x;
    int stride = gridDim.x * blockDim.x;
    for (int i = tid; i < 128 * 64; i += stride) {
        int r = i >> 6, d = i & 63;
        int kind = r >> 6, e = r & 63;
        w1t[i] = f2bf(W1[(kind * 64 + d) * 64 + e]);
    }
    for (int i = tid; i < 64 * 192; i += stride) {
        int r = i / 192, c = i - r * 192;
        wft[i] = f2bf(Wf[c * 64 + r]);
    }
}

// ---- main fused kernel: 32 pixels per block, 4 waves ----
__global__ __launch_bounds__(256, 2) void dig_main(
    const float* __restrict__ x,     // [4][192][65536] fp32
    const float* __restrict__ W1,    // fallback path only
    const float* __restrict__ b1,    // [64]
    const float* __restrict__ W2,    // [64]
    const float* __restrict__ b2,    // [1]
    const float* __restrict__ Wf,    // fallback path only
    const float* __restrict__ bfv,   // [64]
    float* __restrict__ out,         // [4][64][65536] fp32
    const unsigned short* __restrict__ w1t_g,  // [128][64] bf16 (pre-transposed)
    const unsigned short* __restrict__ wft_g,  // [64][192] bf16 (pre-transposed)
    int wsok)
{
    // LDS: 12800 + 25600 + 27648 + 768 + 516 = 67332 B -> 2 blocks/CU
    __shared__ __align__(16) unsigned short XS[32 * 200];   // x tile [pix][c], bf16, pad 192->200
    __shared__ __align__(16) unsigned short WB[64 * 200];   // W1T [128][72] then WfT [64][200]
    __shared__ __align__(16) unsigned short ACT[384 * 36];  // a/c tile [col][pix] bf16; later ACC [32][200]
    __shared__ float GT[6 * 32];                            // gates [pair][pix]
    __shared__ float BW[129];                               // b1 (0..63), W2 (64..127), b2 (128)

    const int tid = threadIdx.x;
    const int l   = tid & 63;
    const int w   = tid >> 6;
    const int lm  = l & 15;     // MFMA lane row/col index
    const int q   = l >> 4;     // MFMA quad

    const int tile = blockIdx.x;
    const int bb   = tile >> 11;
    const int hw0  = (tile & 2047) * 32;

    // ---------- Stage: x tile (transpose fp32[c][pix] -> bf16 XS[pix][c]) ----------
    const float* xbase = x + (size_t)bb * (192 * HW) + hw0;
    for (int idx = tid; idx < 1536; idx += 256) {          // 6 iters
        int c = idx >> 3, pg = idx & 7;
        float4 v = *(const float4*)(xbase + (size_t)c * HW + pg * 4);
        int p0 = pg * 4;
        XS[(p0 + 0) * 200 + c] = f2bf(v.x);
        XS[(p0 + 1) * 200 + c] = f2bf(v.y);
        XS[(p0 + 2) * 200 + c] = f2bf(v.z);
        XS[(p0 + 3) * 200 + c] = f2bf(v.w);
    }
    // W1T -> WB as [128][72]
    if (wsok) {
        for (int idx = tid; idx < 1024; idx += 256) {      // 4 iters, 16B chunks
            int r = idx >> 3, ch = idx & 7;
            uint4 v = *(const uint4*)(w1t_g + idx * 8);
            *(uint4*)&WB[r * 72 + ch * 8] = v;
        }
    } else {
        for (int idx = tid; idx < 8192; idx += 256) {
            int r = idx >> 6, d = idx & 63;
            int kind = r >> 6, e = r & 63;
            WB[r * 72 + d] = f2bf(W1[(kind * 64 + d) * 64 + e]);
        }
    }
    if (tid < 64)        BW[tid] = b1[tid];
    else if (tid < 128)  BW[tid] = W2[tid - 64];
    else if (tid == 128) BW[128] = b2[0];
    __syncthreads();

    // ---------- Phase B: a/c = X @ W1 via MFMA ----------
    // wave w handles n-tiles {2w, 2w+1}; m-tiles 0,1; t 0..2; K=64 (2 k-steps)
    {
        short8 bfr[2][2];
        #pragma unroll
        for (int ntl = 0; ntl < 2; ++ntl)
            #pragma unroll
            for (int ks = 0; ks < 2; ++ks)
                bfr[ntl][ks] = *(const short8*)&WB[((2 * w + ntl) * 16 + lm) * 72 + ks * 32 + q * 8];

        for (int t = 0; t < 3; ++t) {
            short8 afr[2][2];
            #pragma unroll
            for (int mt = 0; mt < 2; ++mt)
                #pragma unroll
                for (int ks = 0; ks < 2; ++ks)
                    afr[mt][ks] = *(const short8*)&XS[(mt * 16 + lm) * 200 + t * 64 + ks * 32 + q * 8];

            f32x4 acc[2][2];
            #pragma unroll
            for (int mt = 0; mt < 2; ++mt)
                #pragma unroll
                for (int ntl = 0; ntl < 2; ++ntl) {
                    acc[mt][ntl] = (f32x4){0.f, 0.f, 0.f, 0.f};
                    acc[mt][ntl] = __builtin_amdgcn_mfma_f32_16x16x32_bf16(
                        afr[mt][0], bfr[ntl][0], acc[mt][ntl], 0, 0, 0);
                    acc[mt][ntl] = __builtin_amdgcn_mfma_f32_16x16x32_bf16(
                        afr[mt][1], bfr[ntl][1], acc[mt][ntl], 0, 0, 0);
                }

            // epilogue: D[m=pix][n=e-col] -> ACT[col][pix], 4 consecutive pix per lane
            #pragma unroll
            for (int mt = 0; mt < 2; ++mt)
                #pragma unroll
                for (int ntl = 0; ntl < 2; ++ntl) {
                    int col  = t * 128 + (2 * w + ntl) * 16 + lm;
                    int pix0 = mt * 16 + q * 4;
                    ushort4 pk = make_ushort4(f2bf(acc[mt][ntl][0]), f2bf(acc[mt][ntl][1]),
                                              f2bf(acc[mt][ntl][2]), f2bf(acc[mt][ntl][3]));
                    *(ushort4*)&ACT[col * 36 + pix0] = pk;
                }
        }
    }
    __syncthreads();

    // ---------- Phase C: gates (waves 0-2) || WfT staging (wave 3) ----------
    if (tid < 192) {
        const int pr  = tid >> 5;
        const int pix = tid & 31;
        const int i   = pr >> 1;
        const int j0c = (i == 0) ? 1 : 0;
        const int j1c = (i == 2) ? 1 : 2;
        const int j   = (pr & 1) ? j1c : j0c;

        const unsigned short* arow = ACT + (i * 128) * 36 + pix;
        const unsigned short* crow = ACT + (j * 128 + 64) * 36 + pix;
        float g = 0.f;
        #pragma unroll 4
        for (int e = 0; e < 64; ++e) {
            float h = bf2f(arow[e * 36]) + bf2f(crow[e * 36]) + BW[e];
            // tanh-form gelu (|err| <= ~3e-3, well inside tolerance)
            float u  = 0.7978845608f * (h + 0.044715f * h * h * h);
            float ex = __expf(2.0f * u);
            float th = 1.0f - 2.0f / (ex + 1.0f);
            g += BW[64 + e] * (0.5f * h * (1.0f + th));
        }
        g += BW[128];
        GT[pr * 32 + pix] = 1.0f / (1.0f + __expf(-g));
    } else {
        // wave 3: stage WfT into WB (W1T is dead after phase B)
        if (wsok) {
            for (int i2 = l; i2 < 1536; i2 += 64) {
                int r = i2 / 24, ch = i2 - r * 24;
                uint4 v = *(const uint4*)(wft_g + i2 * 8);
                *(uint4*)&WB[r * 200 + ch * 8] = v;
            }
        } else {
            for (int idx = l; idx < 12288; idx += 64) {
                int r = idx / 192, c = idx - r * 192;
                WB[r * 200 + c] = f2bf(Wf[c * 64 + r]);
            }
        }
    }
    __syncthreads();

    // ---------- Phase D: acc_i[d] = x_i[d] + g0*x_j0[d] + g1*x_j1[d] -> ACC bf16 ----------
    {
        unsigned short* ACC = ACT;        // reuse (first 32*200 shorts)
        const int pix = tid >> 3;
        const int cg  = tid & 7;
        #pragma unroll
        for (int ch = 0; ch < 6; ++ch) {
            int c0 = cg * 24 + ch * 4;    // never crosses a 64-boundary
            int i  = c0 >> 6, d = c0 & 63;
            int j0c = (i == 0) ? 1 : 0;
            int j1c = (i == 2) ? 1 : 2;
            float g0 = GT[(2 * i) * 32 + pix];
            float g1 = GT[(2 * i + 1) * 32 + pix];
            ushort4 xi  = *(const ushort4*)&XS[pix * 200 + i * 64 + d];
            ushort4 xj0 = *(const ushort4*)&XS[pix * 200 + j0c * 64 + d];
            ushort4 xj1 = *(const ushort4*)&XS[pix * 200 + j1c * 64 + d];
            ushort4 o;
            o.x = f2bf(bf2f(xi.x) + g0 * bf2f(xj0.x) + g1 * bf2f(xj1.x));
            o.y = f2bf(bf2f(xi.y) + g0 * bf2f(xj0.y) + g1 * bf2f(xj1.y));
            o.z = f2bf(bf2f(xi.z) + g0 * bf2f(xj0.z) + g1 * bf2f(xj1.z));
            o.w = f2bf(bf2f(xi.w) + g0 * bf2f(xj0.w) + g1 * bf2f(xj1.w));
            *(ushort4*)&ACC[pix * 200 + c0] = o;
        }
    }
    __syncthreads();

    // ---------- Phase E: out = ACC @ Wf + bf via MFMA (K=192, 6 k-steps) ----------
    {
        const unsigned short* ACC = ACT;
        const int mt  = w >> 1;
        const int ntb = (w & 1) * 2;
        f32x4 acc[2];
        acc[0] = (f32x4){0.f, 0.f, 0.f, 0.f};
        acc[1] = (f32x4){0.f, 0.f, 0.f, 0.f};
        #pragma unroll
        for (int ks = 0; ks < 6; ++ks) {
            short8 af = *(const short8*)&ACC[(mt * 16 + lm) * 200 + ks * 32 + q * 8];
            #pragma unroll
            for (int ntl = 0; ntl < 2; ++ntl) {
                short8 bfw = *(const short8*)&WB[((ntb + ntl) * 16 + lm) * 200 + ks * 32 + q * 8];
                acc[ntl] = __builtin_amdgcn_mfma_f32_16x16x32_bf16(af, bfw, acc[ntl], 0, 0, 0);
            }
        }
        #pragma unroll
        for (int ntl = 0; ntl < 2; ++ntl) {
            int o = (ntb + ntl) * 16 + lm;
            float bo = bfv[o];
            float* obase = out + (size_t)bb * (64 * HW) + (size_t)o * HW + hw0 + mt * 16 + q * 4;
            *(float4*)obase = make_float4(acc[ntl][0] + bo, acc[ntl][1] + bo,
                                          acc[ntl][2] + bo, acc[ntl][3] + bo);
        }
    }
}

extern "C" void kernel_launch(void* const* d_in, const int* in_sizes, int n_in,
                              void* d_out, int out_size, void* d_ws, size_t ws_size,
                              hipStream_t stream) {
    (void)in_sizes; (void)n_in; (void)out_size;
    const float* x  = (const float*)d_in[0];
    const float* W1 = (const float*)d_in[1];
    const float* b1 = (const float*)d_in[2];
    const float* W2 = (const float*)d_in[3];
    const float* b2 = (const float*)d_in[4];
    const float* Wf = (const float*)d_in[5];
    const float* bf = (const float*)d_in[6];
    float* out = (float*)d_out;

    unsigned short* w1t = (unsigned short*)d_ws;
    unsigned short* wft = w1t + 128 * 64;
    const size_t need = (size_t)(128 * 64 + 64 * 192) * sizeof(unsigned short);
    int wsok = (d_ws != nullptr && ws_size >= need) ? 1 : 0;

    if (wsok) dig_prep<<<dim3(80), dim3(256), 0, stream>>>(W1, Wf, w1t, wft);
    dig_main<<<dim3(8192), dim3(256), 0, stream>>>(x, W1, b1, W2, b2, Wf, bf, out,
                                                   w1t, wft, wsok);
}

// Round 3
// 370.356 us; speedup vs baseline: 2.1829x; 1.2015x over previous
//
#include <hip/hip_runtime.h>

#define HW 65536

typedef __attribute__((ext_vector_type(8))) short short8;   // 8 bf16 = 4 VGPRs (MFMA A/B frag)
typedef __attribute__((ext_vector_type(4))) float f32x4;    // MFMA C/D frag

static __device__ __forceinline__ unsigned short f2bf(float f) {
    unsigned int u = __float_as_uint(f);
    u += 0x7FFFu + ((u >> 16) & 1u);        // round-to-nearest-even (inputs finite)
    return (unsigned short)(u >> 16);
}
static __device__ __forceinline__ float bf2f(unsigned short s) {
    return __uint_as_float(((unsigned int)s) << 16);
}

// ---- prep: transpose weights to bf16 in workspace ----
// w1t[r][d], r = kind*64 + e (128 rows x 64): = W1[kind*64 + d][e]
// wft[o][c] (64 rows x 192):                  = Wf[c][o]
__global__ void dig_prep(const float* __restrict__ W1, const float* __restrict__ Wf,
                         unsigned short* __restrict__ w1t, unsigned short* __restrict__ wft) {
    int tid = blockIdx.x * blockDim.x + threadIdx.x;
    int stride = gridDim.x * blockDim.x;
    for (int i = tid; i < 128 * 64; i += stride) {
        int r = i >> 6, d = i & 63;
        int kind = r >> 6, e = r & 63;
        w1t[i] = f2bf(W1[(kind * 64 + d) * 64 + e]);
    }
    for (int i = tid; i < 64 * 192; i += stride) {
        int r = i / 192, c = i - r * 192;
        wft[i] = f2bf(Wf[c * 64 + r]);
    }
}

// ---- main fused kernel: 32 pixels per block, 4 waves ----
// LDS ~27 KB -> 4+ blocks/CU. Gates computed fully in registers from MFMA accs.
__global__ __launch_bounds__(256, 4) void dig_main(
    const float* __restrict__ x,     // [4][192][65536] fp32
    const float* __restrict__ W1,    // fallback path only
    const float* __restrict__ b1,    // [64]
    const float* __restrict__ W2,    // [64]
    const float* __restrict__ b2,    // [1]
    const float* __restrict__ Wf,    // fallback path only
    const float* __restrict__ bfv,   // [64]
    float* __restrict__ out,         // [4][64][65536] fp32
    const unsigned short* __restrict__ w1t_g,  // [128][64] bf16 (pre-transposed)
    const unsigned short* __restrict__ wft_g,  // [64][192] bf16 (pre-transposed)
    int wsok)
{
    __shared__ __align__(16) unsigned short XS[32 * 200];   // 12800 B: x tile [pix][c] bf16
    __shared__ __align__(16) unsigned short ACC[32 * 200];  // 12800 B: gated tile [pix][c] bf16
    __shared__ float GT[192];                               // 768 B: gate pre-acts [pair][pix]
    __shared__ float BW[132];                               // b1(0..63), W2(64..127), b2(128)

    const int tid = threadIdx.x;
    const int l   = tid & 63;
    const int w   = tid >> 6;
    const int lm  = l & 15;     // MFMA lane row/col index
    const int q   = l >> 4;     // MFMA quad

    const int tile = blockIdx.x;
    const int bb   = tile >> 11;
    const int hw0  = (tile & 2047) * 32;

    // ---------- Stage: x tile (transpose fp32[c][pix] -> bf16 XS[pix][c]) ----------
    const float* xbase = x + (size_t)bb * (192 * HW) + hw0;
    for (int idx = tid; idx < 1536; idx += 256) {          // 6 iters
        int c = idx >> 3, pg = idx & 7;
        float4 v = *(const float4*)(xbase + (size_t)c * HW + pg * 4);
        int p0 = pg * 4;
        XS[(p0 + 0) * 200 + c] = f2bf(v.x);
        XS[(p0 + 1) * 200 + c] = f2bf(v.y);
        XS[(p0 + 2) * 200 + c] = f2bf(v.z);
        XS[(p0 + 3) * 200 + c] = f2bf(v.w);
    }
    if (tid < 192)       GT[tid] = 0.f;
    if (tid < 64)        BW[tid] = b1[tid];
    else if (tid < 128)  BW[tid] = W2[tid - 64];
    else if (tid == 128) BW[128] = b2[0];
    __syncthreads();

    // ---------- Phase B: a/c = W1T @ XS^T via MFMA; m = e-rows, n = pix ----------
    // Wave w owns e-range [16w, 16w+16) for BOTH kinds -> gates become register math.
    short8 afr[2][2];   // A frags: [kind][ks], rows = kind*64 + 16w + lm
    if (wsok) {
        #pragma unroll
        for (int kind = 0; kind < 2; ++kind)
            #pragma unroll
            for (int ks = 0; ks < 2; ++ks)
                afr[kind][ks] = *(const short8*)&w1t_g[(kind * 64 + w * 16 + lm) * 64 + ks * 32 + q * 8];
    } else {
        #pragma unroll
        for (int kind = 0; kind < 2; ++kind)
            #pragma unroll
            for (int ks = 0; ks < 2; ++ks) {
                union { short8 v; unsigned short u[8]; } tmp;
                #pragma unroll
                for (int j = 0; j < 8; ++j)
                    tmp.u[j] = f2bf(W1[(kind * 64 + ks * 32 + q * 8 + j) * 64 + (w * 16 + lm)]);
                afr[kind][ks] = tmp.v;
            }
    }

    f32x4 acc[2][3][2];   // [kind][t][pixtile]; lane: e = 16w + 4q + reg, pix = pt*16 + lm
    #pragma unroll
    for (int kind = 0; kind < 2; ++kind)
        #pragma unroll
        for (int t = 0; t < 3; ++t)
            #pragma unroll
            for (int pt = 0; pt < 2; ++pt)
                acc[kind][t][pt] = (f32x4){0.f, 0.f, 0.f, 0.f};

    #pragma unroll
    for (int t = 0; t < 3; ++t) {
        short8 bfr[2][2];   // B frags: [pixtile][ks], rows = pix
        #pragma unroll
        for (int pt = 0; pt < 2; ++pt)
            #pragma unroll
            for (int ks = 0; ks < 2; ++ks)
                bfr[pt][ks] = *(const short8*)&XS[(pt * 16 + lm) * 200 + t * 64 + ks * 32 + q * 8];
        #pragma unroll
        for (int kind = 0; kind < 2; ++kind)
            #pragma unroll
            for (int pt = 0; pt < 2; ++pt) {
                acc[kind][t][pt] = __builtin_amdgcn_mfma_f32_16x16x32_bf16(
                    afr[kind][0], bfr[pt][0], acc[kind][t][pt], 0, 0, 0);
                acc[kind][t][pt] = __builtin_amdgcn_mfma_f32_16x16x32_bf16(
                    afr[kind][1], bfr[pt][1], acc[kind][t][pt], 0, 0, 0);
            }
    }

    // ---------- Phase C: gate partials in registers, reduce over e ----------
    {
        float4 b1v4 = *(const float4*)&BW[w * 16 + q * 4];
        float4 w2v4 = *(const float4*)&BW[64 + w * 16 + q * 4];
        const float b1a[4] = {b1v4.x, b1v4.y, b1v4.z, b1v4.w};
        const float w2a[4] = {w2v4.x, w2v4.y, w2v4.z, w2v4.w};
        #pragma unroll
        for (int pr = 0; pr < 6; ++pr) {
            const int i   = pr >> 1;
            const int j0c = (i == 0) ? 1 : 0;
            const int j1c = (i == 2) ? 1 : 2;
            const int j   = (pr & 1) ? j1c : j0c;
            #pragma unroll
            for (int pt = 0; pt < 2; ++pt) {
                float p = 0.f;
                #pragma unroll
                for (int r = 0; r < 4; ++r) {
                    float h  = acc[0][i][pt][r] + acc[1][j][pt][r] + b1a[r];
                    float h2 = h * h;
                    // tanh-form gelu (|err| <= ~3e-3, well inside tolerance)
                    float u  = 0.7978845608f * __builtin_fmaf(0.044715f * h2, h, h);
                    float ex = __expf(2.0f * u);
                    float th = 1.0f - 2.0f / (ex + 1.0f);
                    float ge = 0.5f * h * (1.0f + th);
                    p = __builtin_fmaf(w2a[r], ge, p);
                }
                // reduce over q (e-dimension): lanes l, l^16, l^32, l^48
                p += __shfl_xor(p, 16);
                p += __shfl_xor(p, 32);
                if (l < 16) atomicAdd(&GT[pr * 32 + pt * 16 + lm], p);  // cross-wave e-sum
            }
        }
    }
    __syncthreads();

    // ---------- Phase D: ACC[pix][i*64+d] = x_i + g0*x_j0 + g1*x_j1 (bf16) ----------
    {
        const int pix = tid >> 3;
        const int cg  = tid & 7;
        const float b2v = BW[128];
        const unsigned short* xrow = XS + pix * 200;
        unsigned short* arow = ACC + pix * 200;
        #pragma unroll
        for (int i = 0; i < 3; ++i) {
            const int j0c = (i == 0) ? 1 : 0;
            const int j1c = (i == 2) ? 1 : 2;
            float g0 = 1.0f / (1.0f + __expf(-(GT[(2 * i + 0) * 32 + pix] + b2v)));
            float g1 = 1.0f / (1.0f + __expf(-(GT[(2 * i + 1) * 32 + pix] + b2v)));
            #pragma unroll
            for (int ch = 0; ch < 2; ++ch) {
                int d0 = cg * 4 + ch * 32;
                ushort4 xi  = *(const ushort4*)&xrow[i * 64 + d0];
                ushort4 xj0 = *(const ushort4*)&xrow[j0c * 64 + d0];
                ushort4 xj1 = *(const ushort4*)&xrow[j1c * 64 + d0];
                ushort4 o;
                o.x = f2bf(bf2f(xi.x) + g0 * bf2f(xj0.x) + g1 * bf2f(xj1.x));
                o.y = f2bf(bf2f(xi.y) + g0 * bf2f(xj0.y) + g1 * bf2f(xj1.y));
                o.z = f2bf(bf2f(xi.z) + g0 * bf2f(xj0.z) + g1 * bf2f(xj1.z));
                o.w = f2bf(bf2f(xi.w) + g0 * bf2f(xj0.w) + g1 * bf2f(xj1.w));
                *(ushort4*)&arow[i * 64 + d0] = o;
            }
        }
    }
    __syncthreads();

    // ---------- Phase E: out = ACC @ Wf + bf via MFMA; b-frags direct from global ----------
    {
        const int mt  = w >> 1;
        const int ntb = (w & 1) * 2;
        f32x4 eacc[2];
        eacc[0] = (f32x4){0.f, 0.f, 0.f, 0.f};
        eacc[1] = (f32x4){0.f, 0.f, 0.f, 0.f};
        #pragma unroll
        for (int ks = 0; ks < 6; ++ks) {
            short8 af = *(const short8*)&ACC[(mt * 16 + lm) * 200 + ks * 32 + q * 8];
            #pragma unroll
            for (int ntl = 0; ntl < 2; ++ntl) {
                short8 bw8;
                if (wsok) {
                    bw8 = *(const short8*)&wft_g[((ntb + ntl) * 16 + lm) * 192 + ks * 32 + q * 8];
                } else {
                    union { short8 v; unsigned short u[8]; } tmp;
                    #pragma unroll
                    for (int j = 0; j < 8; ++j)
                        tmp.u[j] = f2bf(Wf[(ks * 32 + q * 8 + j) * 64 + (ntb + ntl) * 16 + lm]);
                    bw8 = tmp.v;
                }
                eacc[ntl] = __builtin_amdgcn_mfma_f32_16x16x32_bf16(af, bw8, eacc[ntl], 0, 0, 0);
            }
        }
        #pragma unroll
        for (int ntl = 0; ntl < 2; ++ntl) {
            int o = (ntb + ntl) * 16 + lm;
            float bo = bfv[o];
            float* obase = out + (size_t)bb * (64 * HW) + (size_t)o * HW + hw0 + mt * 16 + q * 4;
            *(float4*)obase = make_float4(eacc[ntl][0] + bo, eacc[ntl][1] + bo,
                                          eacc[ntl][2] + bo, eacc[ntl][3] + bo);
        }
    }
}

extern "C" void kernel_launch(void* const* d_in, const int* in_sizes, int n_in,
                              void* d_out, int out_size, void* d_ws, size_t ws_size,
                              hipStream_t stream) {
    (void)in_sizes; (void)n_in; (void)out_size;
    const float* x  = (const float*)d_in[0];
    const float* W1 = (const float*)d_in[1];
    const float* b1 = (const float*)d_in[2];
    const float* W2 = (const float*)d_in[3];
    const float* b2 = (const float*)d_in[4];
    const float* Wf = (const float*)d_in[5];
    const float* bf = (const float*)d_in[6];
    float* out = (float*)d_out;

    unsigned short* w1t = (unsigned short*)d_ws;
    unsigned short* wft = w1t + 128 * 64;
    const size_t need = (size_t)(128 * 64 + 64 * 192) * sizeof(unsigned short);
    int wsok = (d_ws != nullptr && ws_size >= need) ? 1 : 0;

    if (wsok) dig_prep<<<dim3(80), dim3(256), 0, stream>>>(W1, Wf, w1t, wft);
    dig_main<<<dim3(8192), dim3(256), 0, stream>>>(x, W1, b1, W2, b2, Wf, bf, out,
                                                   w1t, wft, wsok);
}